// Round 2
// baseline (624.762 us; speedup 1.0000x reference)
//
#include <hip/hip_runtime.h>

// NAM: out[b,c] = bias[c] + sum_f Wout[f]^T · relu(W2[f]^T · relu(x[b,f]*W1[f] + b1[f]) + b2[f])
// B=8192, F=256, H1=64, H2=32, C=10. fp32 (no fp32-input MFMA on CDNA4 -> vector FMA).
//
// Structure: block = (row-group, feature-group). Weights for one feature staged in LDS
// (broadcast reads), reused across RPT=2 rows/thread -> inner loop ~90% v_fma issue.
// Partial sums per feature-group -> d_ws, reduced by second kernel (no atomics).

#define NB 8192
#define NF 256
#define H1 64
#define H2 32
#define NC 10
#define THREADS 256
#define RPT 2
#define ROWSPB (THREADS * RPT)   // 512 rows per block
#define NRG (NB / ROWSPB)        // 16 row-groups
#define FPG 4                    // features per block
#define NFG (NF / FPG)           // 64 feature-groups

template <bool USE_WS>
__global__ __launch_bounds__(THREADS, 2) void nam_partial(
    const float* __restrict__ x,  const float* __restrict__ W1,
    const float* __restrict__ b1, const float* __restrict__ W2,
    const float* __restrict__ b2, const float* __restrict__ Wout,
    float* __restrict__ dst) {   // USE_WS: ws partials [NFG][NB][NC]; else: out (atomics)
    __shared__ float sW2[H1 * H2];   // 8 KB
    __shared__ float sWo[H2 * NC];   // 1.25 KB
    __shared__ float sW1[H1];
    __shared__ float sB1[H1];
    __shared__ float sB2[H2];

    const int t  = threadIdx.x;
    const int rg = blockIdx.x, fg = blockIdx.y;
    const int r0 = rg * ROWSPB + t;       // first row
    const int r1 = r0 + THREADS;          // second row
    const int f0 = fg * FPG;

    // One float4 per row covers this block's 4 features (f0 % 4 == 0 -> 16B aligned).
    const float4 xa = *(const float4*)(x + (size_t)r0 * NF + f0);
    const float4 xb = *(const float4*)(x + (size_t)r1 * NF + f0);
    const float xr0[FPG] = {xa.x, xa.y, xa.z, xa.w};
    const float xr1[FPG] = {xb.x, xb.y, xb.z, xb.w};

    float acc0[NC], acc1[NC];
#pragma unroll
    for (int c = 0; c < NC; ++c) { acc0[c] = 0.f; acc1[c] = 0.f; }

#pragma unroll   // full unroll: keeps xr0/xr1 indexing compile-time (no scratch)
    for (int ff = 0; ff < FPG; ++ff) {
        const int f = f0 + ff;
        __syncthreads();  // previous iteration done reading LDS
        {
            // Stage this feature's weights (coalesced float4 copies, all 16B-aligned).
            const float4* s2 = (const float4*)(W2 + (size_t)f * H1 * H2);
#pragma unroll
            for (int i = 0; i < 2; ++i)
                ((float4*)sW2)[t + i * THREADS] = s2[t + i * THREADS];
            if (t < H2 * NC / 4) {                       // 80 float4
                ((float4*)sWo)[t] = ((const float4*)(Wout + (size_t)f * H2 * NC))[t];
            } else if (t >= 128 && t < 128 + H1 / 4) {   // 16
                ((float4*)sW1)[t - 128] = ((const float4*)(W1 + (size_t)f * H1))[t - 128];
            } else if (t >= 160 && t < 160 + H1 / 4) {   // 16
                ((float4*)sB1)[t - 160] = ((const float4*)(b1 + (size_t)f * H1))[t - 160];
            } else if (t >= 192 && t < 192 + H2 / 4) {   // 8
                ((float4*)sB2)[t - 192] = ((const float4*)(b2 + (size_t)f * H2))[t - 192];
            }
        }
        __syncthreads();

        float h2a[H2], h2b[H2];
#pragma unroll
        for (int o = 0; o < H2; ++o) { const float bb = sB2[o]; h2a[o] = bb; h2b[o] = bb; }

        const float xv0 = xr0[ff], xv1 = xr1[ff];
#pragma unroll 2
        for (int hh = 0; hh < H1; ++hh) {
            const float a0 = fmaxf(fmaf(xv0, sW1[hh], sB1[hh]), 0.f);
            const float a1 = fmaxf(fmaf(xv1, sW1[hh], sB1[hh]), 0.f);
            const float* wrow = sW2 + hh * H2;
#pragma unroll
            for (int o = 0; o < H2; ++o) {
                const float w = wrow[o];           // LDS broadcast, reused for both rows
                h2a[o] = fmaf(a0, w, h2a[o]);
                h2b[o] = fmaf(a1, w, h2b[o]);
            }
        }

#pragma unroll
        for (int o = 0; o < H2; ++o) {
            const float g0 = fmaxf(h2a[o], 0.f), g1 = fmaxf(h2b[o], 0.f);
            const float* wo = sWo + o * NC;
#pragma unroll
            for (int c = 0; c < NC; ++c) {
                acc0[c] = fmaf(g0, wo[c], acc0[c]);
                acc1[c] = fmaf(g1, wo[c], acc1[c]);
            }
        }
    }

    if (USE_WS) {
        float* p0 = dst + ((size_t)fg * NB + r0) * NC;
        float* p1 = dst + ((size_t)fg * NB + r1) * NC;
#pragma unroll
        for (int c = 0; c < NC; ++c) { p0[c] = acc0[c]; p1[c] = acc1[c]; }
    } else {
        float* p0 = dst + (size_t)r0 * NC;
        float* p1 = dst + (size_t)r1 * NC;
#pragma unroll
        for (int c = 0; c < NC; ++c) { atomicAdd(&p0[c], acc0[c]); atomicAdd(&p1[c], acc1[c]); }
    }
}

__global__ __launch_bounds__(256) void nam_reduce(const float* __restrict__ ws,
                                                  const float* __restrict__ bias,
                                                  float* __restrict__ out) {
    const int i = blockIdx.x * 256 + threadIdx.x;  // over NB*NC
    if (i >= NB * NC) return;
    float s = bias[i % NC];
#pragma unroll 8
    for (int g = 0; g < NFG; ++g) s += ws[(size_t)g * NB * NC + i];
    out[i] = s;
}

__global__ __launch_bounds__(256) void nam_init_out(const float* __restrict__ bias,
                                                    float* __restrict__ out) {
    const int i = blockIdx.x * 256 + threadIdx.x;
    if (i < NB * NC) out[i] = bias[i % NC];
}

extern "C" void kernel_launch(void* const* d_in, const int* in_sizes, int n_in,
                              void* d_out, int out_size, void* d_ws, size_t ws_size,
                              hipStream_t stream) {
    const float* x    = (const float*)d_in[0];
    const float* W1   = (const float*)d_in[1];
    const float* b1   = (const float*)d_in[2];
    const float* W2   = (const float*)d_in[3];
    const float* b2   = (const float*)d_in[4];
    const float* Wout = (const float*)d_in[5];
    const float* bias = (const float*)d_in[6];
    float* out = (float*)d_out;

    const size_t need = (size_t)NFG * NB * NC * sizeof(float);  // 21 MB
    dim3 grid(NRG, NFG);  // 16 x 64 = 1024 blocks

    if (ws_size >= need) {
        nam_partial<true><<<grid, THREADS, 0, stream>>>(x, W1, b1, W2, b2, Wout, (float*)d_ws);
        nam_reduce<<<(NB * NC + 255) / 256, 256, 0, stream>>>((const float*)d_ws, bias, out);
    } else {
        // Fallback: accumulate straight into out with atomics (ws too small).
        nam_init_out<<<(NB * NC + 255) / 256, 256, 0, stream>>>(bias, out);
        nam_partial<false><<<grid, THREADS, 0, stream>>>(x, W1, b1, W2, b2, Wout, out);
    }
}

// Round 4
// 249.842 us; speedup vs baseline: 2.5006x; 2.5006x over previous
//
#include <hip/hip_runtime.h>

// NAM: out[b,c] = bias[c] + sum_f Wout[f]^T · relu(W2[f]^T · relu(x[b,f]*W1[f] + b1[f]) + b2[f])
// B=8192, F=256, H1=64, H2=32, C=10. fp32 (no fp32-input MFMA on CDNA4).
//
// Design: weights are wave-uniform -> compiler scalarizes to s_load (SGPR operands in
// v_fma), zero LDS, zero VALU spent on weight movement (R1 evidence: VGPR=32/SGPR=112).
// One thread = one row x FPG features. Feature-sum across blocks via fp32 partials in
// d_ws (layout [G][C][B] for coalesced store+reduce), tiered by actual ws_size;
// atomics only as last resort (R2 showed 5.2M device atomics = 1.6 GB of RMW traffic).

#define NB 8192
#define NF 256
#define H1 64
#define H2 32
#define NC 10
#define THREADS 256

template <int FPG, bool USE_WS>
__global__ __launch_bounds__(THREADS, 8) void nam_core(
    const float* __restrict__ x,  const float* __restrict__ W1,
    const float* __restrict__ b1, const float* __restrict__ W2,
    const float* __restrict__ b2, const float* __restrict__ Wout,
    float* __restrict__ dst) {  // USE_WS: partials [G][NC][NB]; else out [NB][NC] (atomic)
    const int b  = blockIdx.x * THREADS + threadIdx.x;
    const int fg = blockIdx.y;
    const int f0 = fg * FPG;

    float acc[NC];
#pragma unroll
    for (int c = 0; c < NC; ++c) acc[c] = 0.f;

#pragma unroll 1   // keep body I$-resident; x reload is an L1 hit (64B line = 16 features)
    for (int ff = 0; ff < FPG; ++ff) {
        const int f = f0 + ff;
        const float xv = x[(size_t)b * NF + f];
        // All weight addresses are wave-uniform (blockIdx + loop counter only).
        const float* __restrict__ W1f = W1 + (size_t)f * H1;
        const float* __restrict__ b1f = b1 + (size_t)f * H1;
        const float* __restrict__ W2f = W2 + (size_t)f * (H1 * H2);
        const float* __restrict__ b2f = b2 + (size_t)f * H2;
        const float* __restrict__ Wof = Wout + (size_t)f * (H2 * NC);

        float h2[H2];
#pragma unroll
        for (int o = 0; o < H2; ++o) h2[o] = b2f[o];

        // h1 recomputed per row (2 VALU per 32 FMAs) to keep VGPR <= 64 -> 8 waves/SIMD.
#pragma unroll 16  // lets the compiler batch s_load_dwordx16 ahead of the FMA runs
        for (int hh = 0; hh < H1; ++hh) {
            const float a = fmaxf(fmaf(xv, W1f[hh], b1f[hh]), 0.f);
            const float* wr = W2f + (size_t)hh * H2;
#pragma unroll
            for (int o = 0; o < H2; ++o)
                h2[o] = fmaf(a, wr[o], h2[o]);   // v_fmac v,v,s : 1 SGPR operand, legal
        }

#pragma unroll 8
        for (int o = 0; o < H2; ++o) {
            const float g = fmaxf(h2[o], 0.f);
            const float* wo = Wof + o * NC;
#pragma unroll
            for (int c = 0; c < NC; ++c)
                acc[c] = fmaf(g, wo[c], acc[c]);
        }
    }

    if (USE_WS) {
        // [G][NC][NB]: lane-consecutive b -> 10 fully-coalesced 256B-per-wave stores.
#pragma unroll
        for (int c = 0; c < NC; ++c)
            dst[((size_t)fg * NC + c) * NB + b] = acc[c];
    } else {
        float* orow = dst + (size_t)b * NC;
#pragma unroll
        for (int c = 0; c < NC; ++c) atomicAdd(&orow[c], acc[c]);
    }
}

template <int G>
__global__ __launch_bounds__(256) void nam_reduce(const float* __restrict__ ws,
                                                  const float* __restrict__ bias,
                                                  float* __restrict__ out) {
    const int i = blockIdx.x * 256 + threadIdx.x;  // over [NC][NB]
    const int c = i / NB, b = i % NB;              // lanes: consecutive b, same c
    float s = bias[c];
#pragma unroll 8
    for (int g = 0; g < G; ++g)
        s += ws[((size_t)g * NC + c) * NB + b];    // coalesced across lanes
    out[(size_t)b * NC + c] = s;                   // 0.33 MB scattered write: negligible
}

__global__ __launch_bounds__(256) void nam_init_out(const float* __restrict__ bias,
                                                    float* __restrict__ out) {
    const int i = blockIdx.x * 256 + threadIdx.x;
    if (i < NB * NC) out[i] = bias[i % NC];
}

extern "C" void kernel_launch(void* const* d_in, const int* in_sizes, int n_in,
                              void* d_out, int out_size, void* d_ws, size_t ws_size,
                              hipStream_t stream) {
    const float* x    = (const float*)d_in[0];
    const float* W1   = (const float*)d_in[1];
    const float* b1   = (const float*)d_in[2];
    const float* W2   = (const float*)d_in[3];
    const float* b2   = (const float*)d_in[4];
    const float* Wout = (const float*)d_in[5];
    const float* bias = (const float*)d_in[6];
    float* out = (float*)d_out;

    const size_t need64 = (size_t)64 * NC * NB * sizeof(float);  // 21.0 MB
    const size_t need16 = (size_t)16 * NC * NB * sizeof(float);  //  5.2 MB
    const int nred = (NB * NC + 255) / 256;                      // 320 blocks

    if (ws_size >= need64) {
        // 2048 blocks = 8 blocks/CU x 4 waves = 32 waves/CU (full occupancy).
        nam_core<4, true><<<dim3(NB / THREADS, 64), THREADS, 0, stream>>>(
            x, W1, b1, W2, b2, Wout, (float*)d_ws);
        nam_reduce<64><<<nred, 256, 0, stream>>>((const float*)d_ws, bias, out);
    } else if (ws_size >= need16) {
        nam_core<16, true><<<dim3(NB / THREADS, 16), THREADS, 0, stream>>>(
            x, W1, b1, W2, b2, Wout, (float*)d_ws);
        nam_reduce<16><<<nred, 256, 0, stream>>>((const float*)d_ws, bias, out);
    } else {
        // Last resort: R1-scale atomics (1.3M), known to cost ~42 MB of RMW traffic.
        nam_init_out<<<nred, 256, 0, stream>>>(bias, out);
        nam_core<16, false><<<dim3(NB / THREADS, 16), THREADS, 0, stream>>>(
            x, W1, b1, W2, b2, Wout, out);
    }
}

// Round 5
// 180.145 us; speedup vs baseline: 3.4681x; 1.3869x over previous
//
#include <hip/hip_runtime.h>

// NAM: out[b,c] = bias[c] + sum_f Wout[f]^T · relu(W2[f]^T · relu(x[b,f]*W1[f] + b1[f]) + b2[f])
// B=8192, F=256, H1=64, H2=32, C=10. fp32 (no fp32-input MFMA on CDNA4).
//
// R5: R4 was issue-stalled (VALUBusy 33%, VGPR=32 -> h2 in AGPRs under the 64-VGPR cap;
// x gather = 64 lines/wave thrashing vL1, FETCH 130MB). Fix: (1) pre-transpose x to
// xT[F][B] so x loads are coalesced; (2) launch_bounds(256,4) = 128-VGPR budget + 2
// rows/thread so h2 stays in VGPRs and weight s_loads amortize 2x; (3) grid (fg, rg)
// with fg fastest -> XCD = fg%8 -> per-feature weights pinned to one XCD's L2.

#define NB 8192
#define NF 256
#define H1 64
#define H2 32
#define NC 10
#define THREADS 256
#define ROWSPB (THREADS * 2)     // 2 rows/thread
#define NRG (NB / ROWSPB)        // 16 row-groups
#define FPG 4                    // features per block
#define NFG (NF / FPG)           // 64 feature-groups
#define TS 64                    // transpose tile

// ---- x[B][F] -> xT[F][B], LDS-tiled, fully coalesced both sides ----
__global__ __launch_bounds__(256) void nam_transpose(const float* __restrict__ x,
                                                     float* __restrict__ xT) {
    __shared__ float tile[TS][TS + 1];   // +1 pad: column read = (c0+r)%32 banks, 2-way free
    const int t  = threadIdx.x;
    const int c0 = t & 63;     // lane
    const int r0 = t >> 6;     // wave id 0..3
    const int bb = blockIdx.x * TS;   // batch base
    const int fb = blockIdx.y * TS;   // feature base
#pragma unroll
    for (int k = 0; k < 16; ++k) {
        const int r = r0 + k * 4;
        tile[r][c0] = x[(size_t)(bb + r) * NF + fb + c0];   // 256B/wave, coalesced
    }
    __syncthreads();
#pragma unroll
    for (int k = 0; k < 16; ++k) {
        const int r = r0 + k * 4;   // feature row within tile
        xT[(size_t)(fb + r) * NB + bb + c0] = tile[c0][r];  // coalesced
    }
}

// ---- main: one thread = 2 rows x FPG features; weights via wave-uniform s_load ----
__global__ __launch_bounds__(THREADS, 4) void nam_core_t(
    const float* __restrict__ xT, const float* __restrict__ W1,
    const float* __restrict__ b1, const float* __restrict__ W2,
    const float* __restrict__ b2, const float* __restrict__ Wout,
    float* __restrict__ partial) {   // [NFG][NC][NB]
    const int fg = blockIdx.x;       // fastest dim -> XCD = fg % 8 (L2 weight locality)
    const int rg = blockIdx.y;
    const int t  = threadIdx.x;
    const int r0 = rg * ROWSPB + t;
    const int r1 = r0 + THREADS;
    const int f0 = fg * FPG;

    float acc0[NC], acc1[NC];
#pragma unroll
    for (int c = 0; c < NC; ++c) { acc0[c] = 0.f; acc1[c] = 0.f; }

#pragma unroll 1
    for (int ff = 0; ff < FPG; ++ff) {
        const int f = f0 + ff;
        const float xv0 = xT[(size_t)f * NB + r0];   // coalesced, L2-resident
        const float xv1 = xT[(size_t)f * NB + r1];
        // Wave-uniform weight pointers -> s_load streams, SGPR operands in v_fma.
        const float* __restrict__ W1f = W1 + (size_t)f * H1;
        const float* __restrict__ b1f = b1 + (size_t)f * H1;
        const float* __restrict__ W2f = W2 + (size_t)f * (H1 * H2);
        const float* __restrict__ b2f = b2 + (size_t)f * H2;
        const float* __restrict__ Wof = Wout + (size_t)f * (H2 * NC);

        float h2a[H2], h2b[H2];
#pragma unroll
        for (int o = 0; o < H2; ++o) { const float bb_ = b2f[o]; h2a[o] = bb_; h2b[o] = bb_; }

#pragma unroll 8
        for (int hh = 0; hh < H1; ++hh) {
            const float a0 = fmaxf(fmaf(xv0, W1f[hh], b1f[hh]), 0.f);
            const float a1 = fmaxf(fmaf(xv1, W1f[hh], b1f[hh]), 0.f);
            const float* wr = W2f + (size_t)hh * H2;
#pragma unroll
            for (int o = 0; o < H2; ++o) {
                const float w = wr[o];          // SGPR
                h2a[o] = fmaf(a0, w, h2a[o]);
                h2b[o] = fmaf(a1, w, h2b[o]);
            }
        }

#pragma unroll 8
        for (int o = 0; o < H2; ++o) {
            const float g0 = fmaxf(h2a[o], 0.f), g1 = fmaxf(h2b[o], 0.f);
            const float* wo = Wof + o * NC;
#pragma unroll
            for (int c = 0; c < NC; ++c) {
                const float w = wo[c];
                acc0[c] = fmaf(g0, w, acc0[c]);
                acc1[c] = fmaf(g1, w, acc1[c]);
            }
        }
    }

#pragma unroll
    for (int c = 0; c < NC; ++c) {   // [G][NC][NB]: 256B/wave coalesced stores
        partial[((size_t)fg * NC + c) * NB + r0] = acc0[c];
        partial[((size_t)fg * NC + c) * NB + r1] = acc1[c];
    }
}

// ---- reduce 64 partials + bias -> out[NB][NC]; float4 over b ----
__global__ __launch_bounds__(256) void nam_reduce4(const float* __restrict__ part,
                                                   const float* __restrict__ bias,
                                                   float* __restrict__ out) {
    const int i  = blockIdx.x * 256 + threadIdx.x;   // over NC * NB/4 = 20480
    const int c  = i / (NB / 4);
    const int b4 = i % (NB / 4);
    const float bc = bias[c];
    float4 s = {bc, bc, bc, bc};
#pragma unroll 8
    for (int g = 0; g < NFG; ++g) {
        const float4 v = ((const float4*)(part + ((size_t)g * NC + c) * NB))[b4];
        s.x += v.x; s.y += v.y; s.z += v.z; s.w += v.w;
    }
    const int b = 4 * b4;
    out[(size_t)(b + 0) * NC + c] = s.x;
    out[(size_t)(b + 1) * NC + c] = s.y;
    out[(size_t)(b + 2) * NC + c] = s.z;
    out[(size_t)(b + 3) * NC + c] = s.w;
}

// ---- last-resort fallback (tiny ws): direct x reads + atomics (R1-style) ----
__global__ __launch_bounds__(256) void nam_init_out(const float* __restrict__ bias,
                                                    float* __restrict__ out) {
    const int i = blockIdx.x * 256 + threadIdx.x;
    if (i < NB * NC) out[i] = bias[i % NC];
}

__global__ __launch_bounds__(256) void nam_fallback(
    const float* __restrict__ x,  const float* __restrict__ W1,
    const float* __restrict__ b1, const float* __restrict__ W2,
    const float* __restrict__ b2, const float* __restrict__ Wout,
    float* __restrict__ out) {
    const int b  = blockIdx.x * 256 + threadIdx.x;
    const int f0 = blockIdx.y * 16;
    float acc[NC];
#pragma unroll
    for (int c = 0; c < NC; ++c) acc[c] = 0.f;
#pragma unroll 1
    for (int ff = 0; ff < 16; ++ff) {
        const int f = f0 + ff;
        const float xv = x[(size_t)b * NF + f];
        const float* W1f = W1 + (size_t)f * H1;
        const float* b1f = b1 + (size_t)f * H1;
        const float* W2f = W2 + (size_t)f * (H1 * H2);
        const float* b2f = b2 + (size_t)f * H2;
        const float* Wof = Wout + (size_t)f * (H2 * NC);
        float h2[H2];
#pragma unroll
        for (int o = 0; o < H2; ++o) h2[o] = b2f[o];
#pragma unroll 8
        for (int hh = 0; hh < H1; ++hh) {
            const float a = fmaxf(fmaf(xv, W1f[hh], b1f[hh]), 0.f);
            const float* wr = W2f + (size_t)hh * H2;
#pragma unroll
            for (int o = 0; o < H2; ++o) h2[o] = fmaf(a, wr[o], h2[o]);
        }
#pragma unroll
        for (int o = 0; o < H2; ++o) {
            const float g = fmaxf(h2[o], 0.f);
            const float* wo = Wof + o * NC;
#pragma unroll
            for (int c = 0; c < NC; ++c) acc[c] = fmaf(g, wo[c], acc[c]);
        }
    }
    float* orow = out + (size_t)b * NC;
#pragma unroll
    for (int c = 0; c < NC; ++c) atomicAdd(&orow[c], acc[c]);
}

extern "C" void kernel_launch(void* const* d_in, const int* in_sizes, int n_in,
                              void* d_out, int out_size, void* d_ws, size_t ws_size,
                              hipStream_t stream) {
    const float* x    = (const float*)d_in[0];
    const float* W1   = (const float*)d_in[1];
    const float* b1   = (const float*)d_in[2];
    const float* W2   = (const float*)d_in[3];
    const float* b2   = (const float*)d_in[4];
    const float* Wout = (const float*)d_in[5];
    const float* bias = (const float*)d_in[6];
    float* out = (float*)d_out;

    // ws layout: [xT: NF*NB f32 = 8.4MB][partials: NFG*NC*NB f32 = 21.0MB]
    float* xT   = (float*)d_ws;
    float* part = xT + (size_t)NF * NB;
    const size_t need = ((size_t)NF * NB + (size_t)NFG * NC * NB) * sizeof(float);

    if (ws_size >= need) {
        nam_transpose<<<dim3(NB / TS, NF / TS), 256, 0, stream>>>(x, xT);
        nam_core_t<<<dim3(NFG, NRG), THREADS, 0, stream>>>(xT, W1, b1, W2, b2, Wout, part);
        nam_reduce4<<<(NC * NB / 4 + 255) / 256, 256, 0, stream>>>(part, bias, out);
    } else {
        nam_init_out<<<(NB * NC + 255) / 256, 256, 0, stream>>>(bias, out);
        nam_fallback<<<dim3(NB / 256, 16), 256, 0, stream>>>(x, W1, b1, W2, b2, Wout, out);
    }
}